// Round 10
// baseline (791.152 us; speedup 1.0000x reference)
//
#include <hip/hip_runtime.h>
#include <math.h>

#define BATCH   8
#define SEQ     512
#define IN_DIM  32
#define D_MODEL 512
#define N_LAYERS 4
#define D_INNER 1024
#define D_STATE 16
#define D_CONV  4
#define DT_RANK 32
#define NTOK    (BATCH * SEQ)   // 4096
#define CHUNK   128             // scan L-chunk staged in LDS

typedef __attribute__((ext_vector_type(8))) short short8_t;
typedef __attribute__((ext_vector_type(4))) float floatx4;

__device__ __forceinline__ float sigmoidf_(float x) { return 1.f / (1.f + __expf(-x)); }

// fp32 -> bf16 round-to-nearest-even (finite inputs)
__device__ __forceinline__ unsigned short f2bf(float f) {
    unsigned int u = __float_as_uint(f);
    return (unsigned short)((u + 0x7fffu + ((u >> 16) & 1u)) >> 16);
}
__device__ __forceinline__ float bf2f(unsigned short u) {
    return __uint_as_float((unsigned int)u << 16);
}

// sum x across each 16-lane row group via DPP (VALU pipe, no LDS traffic)
__device__ __forceinline__ float rowsum16(float x) {
    int t;
    t = __builtin_amdgcn_update_dpp(0, __float_as_int(x), 0xB1, 0xF, 0xF, true);  // quad_perm [1,0,3,2]
    x += __int_as_float(t);
    t = __builtin_amdgcn_update_dpp(0, __float_as_int(x), 0x4E, 0xF, 0xF, true);  // quad_perm [2,3,0,1]
    x += __int_as_float(t);
    t = __builtin_amdgcn_update_dpp(0, __float_as_int(x), 0x124, 0xF, 0xF, true); // row_ror:4
    x += __int_as_float(t);
    t = __builtin_amdgcn_update_dpp(0, __float_as_int(x), 0x128, 0xF, 0xF, true); // row_ror:8
    x += __int_as_float(t);
    return x;
}

// one-shot fp32->bf16 cast of the three MFMA weight tensors (single dispatch)
__global__ __launch_bounds__(256) void cast_all_kernel(
    const float* __restrict__ a, unsigned short* __restrict__ oa, int qa,   // vec4 counts
    const float* __restrict__ b, unsigned short* __restrict__ ob, int qb,
    const float* __restrict__ c, unsigned short* __restrict__ oc, int qc)
{
    int v = blockIdx.x * 256 + threadIdx.x;
    const float* in; unsigned short* out;
    if (v < qa)                { in = a; out = oa; }
    else if (v < qa + qb)      { v -= qa; in = b; out = ob; }
    else if (v < qa + qb + qc) { v -= qa + qb; in = c; out = oc; }
    else return;
    const float4 x = *(const float4*)&in[v * 4];
    ushort4 o;
    o.x = f2bf(x.x); o.y = f2bf(x.y); o.z = f2bf(x.z); o.w = f2bf(x.w);
    *(ushort4*)&out[v * 4] = o;
}

// ---------------- bf16 MFMA GEMM ----------------
// OUTBF=false: C fp32, optional residual R. OUTBF=true: C bf16 (no residual).
// ILV: remap output columns 32..63 to interleaved (B0,C0,B1,C1,...) for the scan.
template<int BM, int BN, bool OUTBF, bool ILV>
__global__ __launch_bounds__(256) void gemm_mfma(
    const unsigned short* __restrict__ A, int lda,
    const unsigned short* __restrict__ W, int ldw,
    const float* __restrict__ R,
    void* __restrict__ Cv, int ldc,
    int K)
{
    constexpr int MT = BM / 32;
    constexpr int NT = BN / 32;
    constexpr int LDSP = 40;
    __shared__ __align__(16) unsigned short sA[BM * LDSP];
    __shared__ __align__(16) unsigned short sB[BN * LDSP];

    const int tid  = threadIdx.x;
    const int lane = tid & 63;
    const int wave = tid >> 6;
    const int wm0  = (wave >> 1) * (BM / 2);
    const int wn0  = (wave & 1) * (BN / 2);
    const int lrow = lane & 15;
    const int lko  = (lane >> 4) * 8;
    const int m0 = blockIdx.y * BM;
    const int n0 = blockIdx.x * BN;

    floatx4 acc[MT][NT];
    #pragma unroll
    for (int mt = 0; mt < MT; ++mt)
        #pragma unroll
        for (int nt = 0; nt < NT; ++nt)
            acc[mt][nt] = (floatx4){0.f, 0.f, 0.f, 0.f};

    for (int k0 = 0; k0 < K; k0 += 32) {
        #pragma unroll
        for (int it = 0; it < BM * 4 / 256; ++it) {
            const int idx = it * 256 + tid;
            const int r = idx >> 2, c = (idx & 3) * 8;
            *(short8_t*)&sA[r * LDSP + c] = *(const short8_t*)&A[(size_t)(m0 + r) * lda + k0 + c];
        }
        #pragma unroll
        for (int it = 0; it < BN * 4 / 256; ++it) {
            const int idx = it * 256 + tid;
            const int r = idx >> 2, c = (idx & 3) * 8;
            *(short8_t*)&sB[r * LDSP + c] = *(const short8_t*)&W[(size_t)(n0 + r) * ldw + k0 + c];
        }
        __syncthreads();
        short8_t af[MT], bfr[NT];
        #pragma unroll
        for (int mt = 0; mt < MT; ++mt)
            af[mt] = *(const short8_t*)&sA[(wm0 + mt * 16 + lrow) * LDSP + lko];
        #pragma unroll
        for (int nt = 0; nt < NT; ++nt)
            bfr[nt] = *(const short8_t*)&sB[(wn0 + nt * 16 + lrow) * LDSP + lko];
        #pragma unroll
        for (int mt = 0; mt < MT; ++mt)
            #pragma unroll
            for (int nt = 0; nt < NT; ++nt)
                acc[mt][nt] = __builtin_amdgcn_mfma_f32_16x16x32_bf16(af[mt], bfr[nt], acc[mt][nt], 0, 0, 0);
        __syncthreads();
    }

    #pragma unroll
    for (int mt = 0; mt < MT; ++mt) {
        const int mbase = m0 + wm0 + mt * 16 + (lane >> 4) * 4;
        #pragma unroll
        for (int nt = 0; nt < NT; ++nt) {
            const int n = n0 + wn0 + nt * 16 + (lane & 15);
            int np = n;
            if (ILV) np = (n < 32) ? n : ((n < 48) ? 32 + 2 * (n - 32) : 33 + 2 * (n - 48));
            #pragma unroll
            for (int r = 0; r < 4; ++r) {
                float v = acc[mt][nt][r];
                if (OUTBF) {
                    ((unsigned short*)Cv)[(size_t)(mbase + r) * ldc + np] = f2bf(v);
                } else {
                    if (R) v += R[(size_t)(mbase + r) * ldc + np];
                    ((float*)Cv)[(size_t)(mbase + r) * ldc + np] = v;
                }
            }
        }
    }
}

// ---------------- fp32 vector GEMM (encoder only) ----------------
__global__ __launch_bounds__(256) void gemm_bt64(
    const float* __restrict__ A, int lda,
    const float* __restrict__ W,
    const float* __restrict__ bias,
    float* __restrict__ C,
    int N, int K, int ldc)
{
    __shared__ __align__(16) float As[16][64];
    __shared__ __align__(16) float Ws[16][64];
    const int tid = threadIdx.x;
    const int tx = tid & 15, ty = tid >> 4;
    const int m0 = blockIdx.y * 64, n0 = blockIdx.x * 64;
    const int lm = tid >> 2;
    const int lk = (tid & 3) * 4;

    float acc[4][4] = {};
    for (int k0 = 0; k0 < K; k0 += 16) {
        float4 av = *(const float4*)&A[(size_t)(m0 + lm) * lda + k0 + lk];
        float4 wv = *(const float4*)&W[(size_t)(n0 + lm) * K   + k0 + lk];
        As[lk + 0][lm] = av.x; As[lk + 1][lm] = av.y; As[lk + 2][lm] = av.z; As[lk + 3][lm] = av.w;
        Ws[lk + 0][lm] = wv.x; Ws[lk + 1][lm] = wv.y; Ws[lk + 2][lm] = wv.z; Ws[lk + 3][lm] = wv.w;
        __syncthreads();
        #pragma unroll
        for (int k = 0; k < 16; ++k) {
            float4 a4 = *(const float4*)&As[k][ty * 4];
            float4 b4 = *(const float4*)&Ws[k][tx * 4];
            float a[4] = {a4.x, a4.y, a4.z, a4.w};
            float b[4] = {b4.x, b4.y, b4.z, b4.w};
            #pragma unroll
            for (int i = 0; i < 4; ++i)
                #pragma unroll
                for (int j = 0; j < 4; ++j)
                    acc[i][j] = fmaf(a[i], b[j], acc[i][j]);
        }
        __syncthreads();
    }
    #pragma unroll
    for (int i = 0; i < 4; ++i) {
        const int m = m0 + ty * 4 + i;
        #pragma unroll
        for (int j = 0; j < 4; ++j) {
            const int n = n0 + tx * 4 + j;
            C[(size_t)m * ldc + n] = acc[i][j] + bias[n];
        }
    }
}

// xn_bf[tok,:] = bf16( h[tok,:] * rsqrt(mean(h^2)+1e-5) * w )
__global__ __launch_bounds__(256) void rmsnorm_kernel(
    const float* __restrict__ h, const float* __restrict__ w, unsigned short* __restrict__ xn)
{
    const int tok = blockIdx.x, tid = threadIdx.x;
    const float* row = h + (size_t)tok * D_MODEL;
    float v0 = row[tid], v1 = row[tid + 256];
    float s = v0 * v0 + v1 * v1;
    #pragma unroll
    for (int off = 32; off > 0; off >>= 1) s += __shfl_down(s, off, 64);
    __shared__ float ss[4];
    if ((tid & 63) == 0) ss[tid >> 6] = s;
    __syncthreads();
    const float total = ss[0] + ss[1] + ss[2] + ss[3];
    const float scale = rsqrtf(total * (1.f / (float)D_MODEL) + 1e-5f);
    unsigned short* orow = xn + (size_t)tok * D_MODEL;
    orow[tid]       = f2bf(v0 * scale * w[tid]);
    orow[tid + 256] = f2bf(v1 * scale * w[tid + 256]);
}

// causal dwconv + silu over bf16 xz x-half -> xr_bf (bf16). Fully coalesced.
__global__ __launch_bounds__(256) void conv_silu_kernel(
    const unsigned short* __restrict__ xz, const float* __restrict__ cw,
    const float* __restrict__ cb, unsigned short* __restrict__ xr_bf)
{
    const int idx = blockIdx.x * 256 + threadIdx.x;   // over NTOK*D_INNER
    const int d   = idx & (D_INNER - 1);
    const int tok = idx >> 10;
    const int l   = tok & (SEQ - 1);
    float acc = cb[d];
    #pragma unroll
    for (int k = 0; k < D_CONV; ++k) {
        const int t = l - (D_CONV - 1) + k;
        if (t >= 0)
            acc = fmaf(bf2f(xz[(size_t)(tok + t - l) * (2 * D_INNER) + d]), cw[d * D_CONV + k], acc);
    }
    const float v = acc * sigmoidf_(acc);
    xr_bf[(size_t)tok * D_INNER + d] = f2bf(v);
}

// ---------------- fused dt_proj + selective scan + gate ----------------
// LDS-op diet: operands pair-packed for TWO timesteps per b128 read.
//   sDT  [l][36]    : dt rows (delta dot)
//   sBC2 [l2][n]    : float4 (B,C)@2*l2, (B,C)@2*l2+1   (dbc cols 32.. pre-interleaved by x_proj)
//   sDX2 [l2][d]    : float4 (delta,x)@2*l2, (delta,x)@2*l2+1  (17-padded rows)
//   sY2  [l2][d]    : float2 (p0,p1), 17-padded rows
__global__ __launch_bounds__(256) void scan_kernel(
    const float* __restrict__ dbc,   const unsigned short* __restrict__ xrbf,
    const unsigned short* __restrict__ xzbf, const float* __restrict__ dtp_w,
    const float* __restrict__ dtp_b, const float* __restrict__ A_log,
    const float* __restrict__ Dp,    unsigned short* __restrict__ y)
{
    __shared__ __align__(16) float  sDT [CHUNK][36];          // 18.4 KB
    __shared__ __align__(16) float4 sBC2[(CHUNK/2) * 16];     // 16 KB
    __shared__ __align__(16) float4 sDX2[(CHUNK/2) * 17];     // 17.4 KB
    __shared__ __align__(16) float2 sY2 [(CHUNK/2) * 17];     // 8.7 KB
    const int b   = blockIdx.y;
    const int tid = threadIdx.x;
    const int n   = tid & 15;
    const int dl  = tid >> 4;
    const int d0  = blockIdx.x * 16;
    const int dl_c = tid & 15;      // delta-phase channel
    const int lg   = tid >> 4;      // delta-phase l-group (0..15)
    const int prow = tid >> 1, phalf = tid & 1;   // x-staging mapping

    // per-thread dt_proj weight row
    float4 wv[8];
    {
        const float* wr = dtp_w + (size_t)(d0 + dl_c) * DT_RANK;
        #pragma unroll
        for (int q = 0; q < 8; ++q) wv[q] = *(const float4*)&wr[q * 4];
    }
    const float dtb = dtp_b[d0 + dl_c];
    const float An = -__expf(A_log[(size_t)(d0 + dl) * D_STATE + n]);
    // store-phase D row (q = tid&3 fixed per thread)
    const float4 ddv = *(const float4*)&Dp[d0 + (tid & 3) * 4];

    // prefetch registers
    float4 pdt[4];
    float2 pbe[4], pbo[4];
    short8_t pxv;
    ushort4  pzv[2];

    #define LOAD_CHUNK(L0)                                                                  \
    {                                                                                       \
        _Pragma("unroll")                                                                   \
        for (int it = 0; it < 4; ++it) {                                                    \
            const int u = it * 256 + tid;                                                   \
            pdt[it] = *(const float4*)&dbc[((size_t)(b * SEQ + (L0) + (u >> 3))) * 64 + (u & 7) * 4]; \
        }                                                                                   \
        _Pragma("unroll")                                                                   \
        for (int it = 0; it < 4; ++it) {                                                    \
            const int u = it * 256 + tid;                                                   \
            const int l2 = u >> 4, nu = u & 15;                                             \
            pbe[it] = *(const float2*)&dbc[((size_t)(b * SEQ + (L0) + 2 * l2))     * 64 + 32 + 2 * nu]; \
            pbo[it] = *(const float2*)&dbc[((size_t)(b * SEQ + (L0) + 2 * l2 + 1)) * 64 + 32 + 2 * nu]; \
        }                                                                                   \
        pxv = *(const short8_t*)&xrbf[((size_t)(b * SEQ + (L0) + prow)) * D_INNER + d0 + phalf * 8];   \
        _Pragma("unroll")                                                                   \
        for (int it = 0; it < 2; ++it) {                                                    \
            const int u = it * 256 + tid;                                                   \
            pzv[it] = *(const ushort4*)&xzbf[((size_t)(b * SEQ + (L0) + (u >> 2))) * (2 * D_INNER) + D_INNER + d0 + (u & 3) * 4]; \
        }                                                                                   \
    }

    LOAD_CHUNK(0);
    float h = 0.f;
    for (int l0 = 0; l0 < SEQ; l0 += CHUNK) {
        // ---- write prefetched regs to LDS (all b128 except x scatter) ----
        #pragma unroll
        for (int it = 0; it < 4; ++it) {
            const int u = it * 256 + tid;
            *(float4*)&sDT[u >> 3][(u & 7) * 4] = pdt[it];
        }
        #pragma unroll
        for (int it = 0; it < 4; ++it) {
            const int u = it * 256 + tid;
            sBC2[(u >> 4) * 16 + (u & 15)] = make_float4(pbe[it].x, pbe[it].y, pbo[it].x, pbo[it].y);
        }
        {
            const int base = ((prow >> 1) * 17) * 4 + ((prow & 1) ? 3 : 1);
            #pragma unroll
            for (int j = 0; j < 8; ++j)
                ((float*)sDX2)[base + (phalf * 8 + j) * 4] = bf2f((unsigned short)pxv[j]);
        }
        const ushort4 zc0 = pzv[0], zc1 = pzv[1];   // capture z of current chunk
        __syncthreads();

        // issue next chunk's global loads early
        if (l0 + CHUNK < SEQ) LOAD_CHUNK(l0 + CHUNK);

        // ---- delta = softplus(dt @ W + b): lanes read consecutive l ----
        #pragma unroll
        for (int ls = 0; ls < 8; ++ls) {
            const int l = ls * 16 + lg;
            float a = dtb;
            #pragma unroll
            for (int q = 0; q < 8; ++q) {
                const float4 t4 = *(const float4*)&sDT[l][q * 4];
                a = fmaf(t4.x, wv[q].x, a); a = fmaf(t4.y, wv[q].y, a);
                a = fmaf(t4.z, wv[q].z, a); a = fmaf(t4.w, wv[q].w, a);
            }
            const float dlt = (a > 20.f) ? a : log1pf(__expf(a));
            ((float*)sDX2)[((l >> 1) * 17 + dl_c) * 4 + ((l & 1) ? 2 : 0)] = dlt;
        }
        __syncthreads();

        // ---- recurrence: 2 timesteps per iteration, 1 b128 read per array ----
        #pragma unroll 4
        for (int l2 = 0; l2 < CHUNK / 2; ++l2) {
            const float4 dx4 = sDX2[l2 * 17 + dl];
            const float4 bc4 = sBC2[l2 * 16 + n];
            const float e0 = __expf(dx4.x * An);
            h = fmaf(e0, h, dx4.x * dx4.y * bc4.x);
            const float p0 = rowsum16(h * bc4.y);
            const float e1 = __expf(dx4.z * An);
            h = fmaf(e1, h, dx4.z * dx4.w * bc4.z);
            const float p1 = rowsum16(h * bc4.w);
            if (n == 0) sY2[l2 * 17 + dl] = make_float2(p0, p1);
        }
        __syncthreads();

        // ---- store: y = (p + D*x) * silu(z) ----
        #pragma unroll
        for (int it = 0; it < 2; ++it) {
            const int idx = it * 256 + tid;
            const int l = idx >> 2, q = idx & 3;
            const size_t row = (size_t)(b * SEQ + l0 + l);
            const ushort4 zu = (it == 0) ? zc0 : zc1;
            const float zf[4] = {bf2f(zu.x), bf2f(zu.y), bf2f(zu.z), bf2f(zu.w)};
            const float dd[4] = {ddv.x, ddv.y, ddv.z, ddv.w};
            ushort4 o;
            unsigned short* op = (unsigned short*)&o;
            #pragma unroll
            for (int j = 0; j < 4; ++j) {
                const float p  = ((const float*)sY2)[((l >> 1) * 17 + q * 4 + j) * 2 + (l & 1)];
                const float xv = ((const float*)sDX2)[((l >> 1) * 17 + q * 4 + j) * 4 + ((l & 1) ? 3 : 1)];
                const float yv = fmaf(dd[j], xv, p);
                op[j] = f2bf(yv * zf[j] * sigmoidf_(zf[j]));
            }
            *(ushort4*)&y[row * D_INNER + d0 + q * 4] = o;
        }
        __syncthreads();   // store reads sDX2/sY2; next chunk's writes must wait
    }
    #undef LOAD_CHUNK
}

// fused decoder: out[b] = relu(h_last @ w1.T + b1) @ w2 + b2; one block per batch
__global__ __launch_bounds__(256) void dec_kernel(
    const float* __restrict__ h, const float* __restrict__ w1, const float* __restrict__ b1,
    const float* __restrict__ w2, const float* __restrict__ b2, float* __restrict__ out)
{
    __shared__ __align__(16) float hr[D_MODEL];
    __shared__ float part[4];
    const int b = blockIdx.x, j = threadIdx.x;
    const float* row = h + ((size_t)(b * SEQ + SEQ - 1)) * D_MODEL;
    hr[j] = row[j];
    hr[j + 256] = row[j + 256];
    __syncthreads();
    float acc = b1[j];
    const float* wr = w1 + (size_t)j * D_MODEL;
    for (int k = 0; k < D_MODEL; k += 4) {
        const float4 wvv = *(const float4*)&wr[k];
        const float4 hv = *(const float4*)&hr[k];
        acc = fmaf(wvv.x, hv.x, acc); acc = fmaf(wvv.y, hv.y, acc);
        acc = fmaf(wvv.z, hv.z, acc); acc = fmaf(wvv.w, hv.w, acc);
    }
    float s = fmaxf(acc, 0.f) * w2[j];
    #pragma unroll
    for (int off = 32; off > 0; off >>= 1) s += __shfl_down(s, off, 64);
    if ((j & 63) == 0) part[j >> 6] = s;
    __syncthreads();
    if (j == 0) out[b] = part[0] + part[1] + part[2] + part[3] + b2[0];
}

extern "C" void kernel_launch(void* const* d_in, const int* in_sizes, int n_in,
                              void* d_out, int out_size, void* d_ws, size_t ws_size,
                              hipStream_t stream)
{
    const float* x      = (const float*)d_in[0];
    const float* enc_w  = (const float*)d_in[1];
    const float* enc_b  = (const float*)d_in[2];
    const float* in_w   = (const float*)d_in[3];
    const float* conv_w = (const float*)d_in[4];
    const float* conv_b = (const float*)d_in[5];
    const float* xp_w   = (const float*)d_in[6];
    const float* dtp_w  = (const float*)d_in[7];
    const float* dtp_b  = (const float*)d_in[8];
    const float* A_log  = (const float*)d_in[9];
    const float* Dp     = (const float*)d_in[10];
    const float* out_w  = (const float*)d_in[11];
    const float* norm_w = (const float*)d_in[12];
    const float* dec_w1 = (const float*)d_in[13];
    const float* dec_b1 = (const float*)d_in[14];
    const float* dec_w2 = (const float*)d_in[15];
    const float* dec_b2 = (const float*)d_in[16];
    float* out = (float*)d_out;

    // workspace layout
    float* ws    = (float*)d_ws;
    float* h     = ws;                                   // NTOK*512 fp32
    float* dbc   = h + (size_t)NTOK * D_MODEL;           // NTOK*64 fp32
    float* wsend = dbc + (size_t)NTOK * 64;
    unsigned short* xz_bf   = (unsigned short*)(wsend);                              // NTOK*2048
    unsigned short* xn_bf   = xz_bf   + (size_t)NTOK * 2 * D_INNER;                  // NTOK*512
    unsigned short* y_bf    = xn_bf   + (size_t)NTOK * D_MODEL;                      // NTOK*1024
    unsigned short* xr_bf   = y_bf    + (size_t)NTOK * D_INNER;                      // NTOK*1024
    unsigned short* inw_bf  = xr_bf   + (size_t)NTOK * D_INNER;                      // 4*2048*512
    unsigned short* outw_bf = inw_bf  + (size_t)N_LAYERS * 2 * D_INNER * D_MODEL;    // 4*512*1024
    unsigned short* xpw_bf  = outw_bf + (size_t)N_LAYERS * D_MODEL * D_INNER;        // 4*64*1024

    const int qa = N_LAYERS * 2 * D_INNER * D_MODEL / 4;   // in_proj  vec4 count
    const int qb = N_LAYERS * D_MODEL * D_INNER / 4;       // out_proj
    const int qc = N_LAYERS * 64 * D_INNER / 4;            // x_proj
    cast_all_kernel<<<(qa + qb + qc + 255) / 256, 256, 0, stream>>>(
        in_w, inw_bf, qa, out_w, outw_bf, qb, xp_w, xpw_bf, qc);

    // encoder: h = x @ enc_w.T + enc_b   (fp32, K=32)
    gemm_bt64<<<dim3(D_MODEL / 64, NTOK / 64), 256, 0, stream>>>(
        x, IN_DIM, enc_w, enc_b, h, D_MODEL, IN_DIM, D_MODEL);

    for (int i = 0; i < N_LAYERS; ++i) {
        rmsnorm_kernel<<<NTOK, 256, 0, stream>>>(h, norm_w + (size_t)i * D_MODEL, xn_bf);

        // xz = xn @ in_proj_w[i].T  (4096 x 2048, K=512) [bf16 MFMA, bf16 out]
        gemm_mfma<128, 128, true, false><<<dim3(2 * D_INNER / 128, NTOK / 128), 256, 0, stream>>>(
            xn_bf, D_MODEL, inw_bf + (size_t)i * 2 * D_INNER * D_MODEL, D_MODEL,
            nullptr, xz_bf, 2 * D_INNER, D_MODEL);

        // xr_bf = bf16(silu(causal_dwconv(xz x-half) + cb))
        conv_silu_kernel<<<NTOK * D_INNER / 256, 256, 0, stream>>>(
            xz_bf, conv_w + (size_t)i * D_INNER * D_CONV, conv_b + (size_t)i * D_INNER, xr_bf);

        // dbc = xr @ x_proj_w[i].T  (4096 x 64, K=1024) [bf16 MFMA, fp32 out, BC interleaved]
        gemm_mfma<64, 64, false, true><<<dim3(1, NTOK / 64), 256, 0, stream>>>(
            xr_bf, D_INNER, xpw_bf + (size_t)i * 64 * D_INNER, D_INNER,
            nullptr, dbc, 64, D_INNER);

        // fused dt_proj + scan + D skip + silu(z) gate; y -> bf16
        scan_kernel<<<dim3(D_INNER / 16, BATCH), 256, 0, stream>>>(
            dbc, xr_bf, xz_bf,
            dtp_w + (size_t)i * D_INNER * DT_RANK, dtp_b + (size_t)i * D_INNER,
            A_log + (size_t)i * D_INNER * D_STATE, Dp + (size_t)i * D_INNER, y_bf);

        // h = h + y @ out_proj_w[i].T  (4096 x 512, K=1024) [bf16 MFMA, fp32 out + residual]
        gemm_mfma<128, 64, false, false><<<dim3(D_MODEL / 64, NTOK / 128), 256, 0, stream>>>(
            y_bf, D_INNER, outw_bf + (size_t)i * D_MODEL * D_INNER, D_INNER,
            h, h, D_MODEL, D_INNER);
    }

    dec_kernel<<<BATCH, 256, 0, stream>>>(h, dec_w1, dec_b1, dec_w2, dec_b2, out);
}

// Round 11
// 749.867 us; speedup vs baseline: 1.0551x; 1.0551x over previous
//
#include <hip/hip_runtime.h>
#include <math.h>

#define BATCH   8
#define SEQ     512
#define IN_DIM  32
#define D_MODEL 512
#define N_LAYERS 4
#define D_INNER 1024
#define D_STATE 16
#define D_CONV  4
#define DT_RANK 32
#define NTOK    (BATCH * SEQ)   // 4096
#define CHUNK   128             // scan L-chunk staged in LDS

typedef __attribute__((ext_vector_type(8))) short short8_t;
typedef __attribute__((ext_vector_type(4))) float floatx4;

__device__ __forceinline__ float sigmoidf_(float x) { return 1.f / (1.f + __expf(-x)); }

// fp32 -> bf16 round-to-nearest-even (finite inputs)
__device__ __forceinline__ unsigned short f2bf(float f) {
    unsigned int u = __float_as_uint(f);
    return (unsigned short)((u + 0x7fffu + ((u >> 16) & 1u)) >> 16);
}
__device__ __forceinline__ float bf2f(unsigned short u) {
    return __uint_as_float((unsigned int)u << 16);
}

// sum x across each 16-lane row group via DPP (VALU pipe, no LDS traffic)
__device__ __forceinline__ float rowsum16(float x) {
    int t;
    t = __builtin_amdgcn_update_dpp(0, __float_as_int(x), 0xB1, 0xF, 0xF, true);  // quad_perm [1,0,3,2]
    x += __int_as_float(t);
    t = __builtin_amdgcn_update_dpp(0, __float_as_int(x), 0x4E, 0xF, 0xF, true);  // quad_perm [2,3,0,1]
    x += __int_as_float(t);
    t = __builtin_amdgcn_update_dpp(0, __float_as_int(x), 0x124, 0xF, 0xF, true); // row_ror:4
    x += __int_as_float(t);
    t = __builtin_amdgcn_update_dpp(0, __float_as_int(x), 0x128, 0xF, 0xF, true); // row_ror:8
    x += __int_as_float(t);
    return x;
}

// one-shot fp32->bf16 cast of the three MFMA weight tensors (single dispatch)
__global__ __launch_bounds__(256) void cast_all_kernel(
    const float* __restrict__ a, unsigned short* __restrict__ oa, int qa,   // vec4 counts
    const float* __restrict__ b, unsigned short* __restrict__ ob, int qb,
    const float* __restrict__ c, unsigned short* __restrict__ oc, int qc)
{
    int v = blockIdx.x * 256 + threadIdx.x;
    const float* in; unsigned short* out;
    if (v < qa)                { in = a; out = oa; }
    else if (v < qa + qb)      { v -= qa; in = b; out = ob; }
    else if (v < qa + qb + qc) { v -= qa + qb; in = c; out = oc; }
    else return;
    const float4 x = *(const float4*)&in[v * 4];
    ushort4 o;
    o.x = f2bf(x.x); o.y = f2bf(x.y); o.z = f2bf(x.z); o.w = f2bf(x.w);
    *(ushort4*)&out[v * 4] = o;
}

// ---------------- bf16 MFMA GEMM ----------------
// OUTBF=false: C fp32, optional residual R. OUTBF=true: C bf16 (no residual).
// ILV: remap output columns 32..63 to interleaved (B0,C0,B1,C1,...) for the scan.
template<int BM, int BN, bool OUTBF, bool ILV>
__global__ __launch_bounds__(256) void gemm_mfma(
    const unsigned short* __restrict__ A, int lda,
    const unsigned short* __restrict__ W, int ldw,
    const float* __restrict__ R,
    void* __restrict__ Cv, int ldc,
    int K)
{
    constexpr int MT = BM / 32;
    constexpr int NT = BN / 32;
    constexpr int LDSP = 40;
    __shared__ __align__(16) unsigned short sA[BM * LDSP];
    __shared__ __align__(16) unsigned short sB[BN * LDSP];

    const int tid  = threadIdx.x;
    const int lane = tid & 63;
    const int wave = tid >> 6;
    const int wm0  = (wave >> 1) * (BM / 2);
    const int wn0  = (wave & 1) * (BN / 2);
    const int lrow = lane & 15;
    const int lko  = (lane >> 4) * 8;
    const int m0 = blockIdx.y * BM;
    const int n0 = blockIdx.x * BN;

    floatx4 acc[MT][NT];
    #pragma unroll
    for (int mt = 0; mt < MT; ++mt)
        #pragma unroll
        for (int nt = 0; nt < NT; ++nt)
            acc[mt][nt] = (floatx4){0.f, 0.f, 0.f, 0.f};

    for (int k0 = 0; k0 < K; k0 += 32) {
        #pragma unroll
        for (int it = 0; it < BM * 4 / 256; ++it) {
            const int idx = it * 256 + tid;
            const int r = idx >> 2, c = (idx & 3) * 8;
            *(short8_t*)&sA[r * LDSP + c] = *(const short8_t*)&A[(size_t)(m0 + r) * lda + k0 + c];
        }
        #pragma unroll
        for (int it = 0; it < BN * 4 / 256; ++it) {
            const int idx = it * 256 + tid;
            const int r = idx >> 2, c = (idx & 3) * 8;
            *(short8_t*)&sB[r * LDSP + c] = *(const short8_t*)&W[(size_t)(n0 + r) * ldw + k0 + c];
        }
        __syncthreads();
        short8_t af[MT], bfr[NT];
        #pragma unroll
        for (int mt = 0; mt < MT; ++mt)
            af[mt] = *(const short8_t*)&sA[(wm0 + mt * 16 + lrow) * LDSP + lko];
        #pragma unroll
        for (int nt = 0; nt < NT; ++nt)
            bfr[nt] = *(const short8_t*)&sB[(wn0 + nt * 16 + lrow) * LDSP + lko];
        #pragma unroll
        for (int mt = 0; mt < MT; ++mt)
            #pragma unroll
            for (int nt = 0; nt < NT; ++nt)
                acc[mt][nt] = __builtin_amdgcn_mfma_f32_16x16x32_bf16(af[mt], bfr[nt], acc[mt][nt], 0, 0, 0);
        __syncthreads();
    }

    #pragma unroll
    for (int mt = 0; mt < MT; ++mt) {
        const int mbase = m0 + wm0 + mt * 16 + (lane >> 4) * 4;
        #pragma unroll
        for (int nt = 0; nt < NT; ++nt) {
            const int n = n0 + wn0 + nt * 16 + (lane & 15);
            int np = n;
            if (ILV) np = (n < 32) ? n : ((n < 48) ? 32 + 2 * (n - 32) : 33 + 2 * (n - 48));
            #pragma unroll
            for (int r = 0; r < 4; ++r) {
                float v = acc[mt][nt][r];
                if (OUTBF) {
                    ((unsigned short*)Cv)[(size_t)(mbase + r) * ldc + np] = f2bf(v);
                } else {
                    if (R) v += R[(size_t)(mbase + r) * ldc + np];
                    ((float*)Cv)[(size_t)(mbase + r) * ldc + np] = v;
                }
            }
        }
    }
}

// ---------------- fp32 vector GEMM (encoder only) ----------------
__global__ __launch_bounds__(256) void gemm_bt64(
    const float* __restrict__ A, int lda,
    const float* __restrict__ W,
    const float* __restrict__ bias,
    float* __restrict__ C,
    int N, int K, int ldc)
{
    __shared__ __align__(16) float As[16][64];
    __shared__ __align__(16) float Ws[16][64];
    const int tid = threadIdx.x;
    const int tx = tid & 15, ty = tid >> 4;
    const int m0 = blockIdx.y * 64, n0 = blockIdx.x * 64;
    const int lm = tid >> 2;
    const int lk = (tid & 3) * 4;

    float acc[4][4] = {};
    for (int k0 = 0; k0 < K; k0 += 16) {
        float4 av = *(const float4*)&A[(size_t)(m0 + lm) * lda + k0 + lk];
        float4 wv = *(const float4*)&W[(size_t)(n0 + lm) * K   + k0 + lk];
        As[lk + 0][lm] = av.x; As[lk + 1][lm] = av.y; As[lk + 2][lm] = av.z; As[lk + 3][lm] = av.w;
        Ws[lk + 0][lm] = wv.x; Ws[lk + 1][lm] = wv.y; Ws[lk + 2][lm] = wv.z; Ws[lk + 3][lm] = wv.w;
        __syncthreads();
        #pragma unroll
        for (int k = 0; k < 16; ++k) {
            float4 a4 = *(const float4*)&As[k][ty * 4];
            float4 b4 = *(const float4*)&Ws[k][tx * 4];
            float a[4] = {a4.x, a4.y, a4.z, a4.w};
            float b[4] = {b4.x, b4.y, b4.z, b4.w};
            #pragma unroll
            for (int i = 0; i < 4; ++i)
                #pragma unroll
                for (int j = 0; j < 4; ++j)
                    acc[i][j] = fmaf(a[i], b[j], acc[i][j]);
        }
        __syncthreads();
    }
    #pragma unroll
    for (int i = 0; i < 4; ++i) {
        const int m = m0 + ty * 4 + i;
        #pragma unroll
        for (int j = 0; j < 4; ++j) {
            const int n = n0 + tx * 4 + j;
            C[(size_t)m * ldc + n] = acc[i][j] + bias[n];
        }
    }
}

// xn_bf[tok,:] = bf16( h[tok,:] * rsqrt(mean(h^2)+1e-5) * w )
__global__ __launch_bounds__(256) void rmsnorm_kernel(
    const float* __restrict__ h, const float* __restrict__ w, unsigned short* __restrict__ xn)
{
    const int tok = blockIdx.x, tid = threadIdx.x;
    const float* row = h + (size_t)tok * D_MODEL;
    float v0 = row[tid], v1 = row[tid + 256];
    float s = v0 * v0 + v1 * v1;
    #pragma unroll
    for (int off = 32; off > 0; off >>= 1) s += __shfl_down(s, off, 64);
    __shared__ float ss[4];
    if ((tid & 63) == 0) ss[tid >> 6] = s;
    __syncthreads();
    const float total = ss[0] + ss[1] + ss[2] + ss[3];
    const float scale = rsqrtf(total * (1.f / (float)D_MODEL) + 1e-5f);
    unsigned short* orow = xn + (size_t)tok * D_MODEL;
    orow[tid]       = f2bf(v0 * scale * w[tid]);
    orow[tid + 256] = f2bf(v1 * scale * w[tid + 256]);
}

// causal dwconv + silu over bf16 xz x-half -> xr_bf (bf16). Fully coalesced.
__global__ __launch_bounds__(256) void conv_silu_kernel(
    const unsigned short* __restrict__ xz, const float* __restrict__ cw,
    const float* __restrict__ cb, unsigned short* __restrict__ xr_bf)
{
    const int idx = blockIdx.x * 256 + threadIdx.x;   // over NTOK*D_INNER
    const int d   = idx & (D_INNER - 1);
    const int tok = idx >> 10;
    const int l   = tok & (SEQ - 1);
    float acc = cb[d];
    #pragma unroll
    for (int k = 0; k < D_CONV; ++k) {
        const int t = l - (D_CONV - 1) + k;
        if (t >= 0)
            acc = fmaf(bf2f(xz[(size_t)(tok + t - l) * (2 * D_INNER) + d]), cw[d * D_CONV + k], acc);
    }
    const float v = acc * sigmoidf_(acc);
    xr_bf[(size_t)tok * D_INNER + d] = f2bf(v);
}

// ---------------- fused dt_proj + selective scan + gate ----------------
// Delta-dot reads dbc rows DIRECTLY from global (L2-hot, 16-way lane broadcast)
// -> no sDT buffer, no sDT staging, one less barrier. Recurrence operands
// pair-packed (two timesteps per b128 read).
__global__ __launch_bounds__(256) void scan_kernel(
    const float* __restrict__ dbc,   const unsigned short* __restrict__ xrbf,
    const unsigned short* __restrict__ xzbf, const float* __restrict__ dtp_w,
    const float* __restrict__ dtp_b, const float* __restrict__ A_log,
    const float* __restrict__ Dp,    unsigned short* __restrict__ y)
{
    __shared__ __align__(16) float4 sBC2[(CHUNK/2) * 16];     // 16 KB
    __shared__ __align__(16) float4 sDX2[(CHUNK/2) * 17];     // 17.4 KB
    __shared__ __align__(16) float2 sY2 [(CHUNK/2) * 17];     // 8.7 KB
    const int b   = blockIdx.y;
    const int tid = threadIdx.x;
    const int n   = tid & 15;
    const int dl  = tid >> 4;
    const int d0  = blockIdx.x * 16;
    const int dl_c = tid & 15;      // delta-phase channel
    const int lg   = tid >> 4;      // delta-phase l-group (0..15)
    const int prow = tid >> 1, phalf = tid & 1;   // x-staging mapping

    // per-thread dt_proj weight row
    float4 wv[8];
    {
        const float* wr = dtp_w + (size_t)(d0 + dl_c) * DT_RANK;
        #pragma unroll
        for (int q = 0; q < 8; ++q) wv[q] = *(const float4*)&wr[q * 4];
    }
    const float dtb = dtp_b[d0 + dl_c];
    const float An = -__expf(A_log[(size_t)(d0 + dl) * D_STATE + n]);
    // store-phase D row (q = tid&3 fixed per thread)
    const float4 ddv = *(const float4*)&Dp[d0 + (tid & 3) * 4];

    // prefetch registers (B/C pairs, x, z)
    float2 pbe[4], pbo[4];
    short8_t pxv;
    ushort4  pzv[2];

    #define LOAD_CHUNK(L0)                                                                  \
    {                                                                                       \
        _Pragma("unroll")                                                                   \
        for (int it = 0; it < 4; ++it) {                                                    \
            const int u = it * 256 + tid;                                                   \
            const int l2 = u >> 4, nu = u & 15;                                             \
            pbe[it] = *(const float2*)&dbc[((size_t)(b * SEQ + (L0) + 2 * l2))     * 64 + 32 + 2 * nu]; \
            pbo[it] = *(const float2*)&dbc[((size_t)(b * SEQ + (L0) + 2 * l2 + 1)) * 64 + 32 + 2 * nu]; \
        }                                                                                   \
        pxv = *(const short8_t*)&xrbf[((size_t)(b * SEQ + (L0) + prow)) * D_INNER + d0 + phalf * 8];   \
        _Pragma("unroll")                                                                   \
        for (int it = 0; it < 2; ++it) {                                                    \
            const int u = it * 256 + tid;                                                   \
            pzv[it] = *(const ushort4*)&xzbf[((size_t)(b * SEQ + (L0) + (u >> 2))) * (2 * D_INNER) + D_INNER + d0 + (u & 3) * 4]; \
        }                                                                                   \
    }

    LOAD_CHUNK(0);
    float h = 0.f;
    for (int l0 = 0; l0 < SEQ; l0 += CHUNK) {
        // ---- write prefetched regs to LDS ----
        #pragma unroll
        for (int it = 0; it < 4; ++it) {
            const int u = it * 256 + tid;
            sBC2[(u >> 4) * 16 + (u & 15)] = make_float4(pbe[it].x, pbe[it].y, pbo[it].x, pbo[it].y);
        }
        {
            const int base = ((prow >> 1) * 17) * 4 + ((prow & 1) ? 3 : 1);
            #pragma unroll
            for (int j = 0; j < 8; ++j)
                ((float*)sDX2)[base + (phalf * 8 + j) * 4] = bf2f((unsigned short)pxv[j]);
        }
        const ushort4 zc0 = pzv[0], zc1 = pzv[1];   // capture z of current chunk

        // ---- delta = softplus(dt @ W + b): dt rows read from GLOBAL (broadcast) ----
        #pragma unroll
        for (int ls = 0; ls < 8; ++ls) {
            const int l = ls * 16 + lg;
            const float* dtrow = &dbc[((size_t)(b * SEQ + l0 + l)) * 64];
            float a = dtb;
            #pragma unroll
            for (int q = 0; q < 8; ++q) {
                const float4 t4 = *(const float4*)&dtrow[q * 4];
                a = fmaf(t4.x, wv[q].x, a); a = fmaf(t4.y, wv[q].y, a);
                a = fmaf(t4.z, wv[q].z, a); a = fmaf(t4.w, wv[q].w, a);
            }
            const float dlt = (a > 20.f) ? a : log1pf(__expf(a));
            ((float*)sDX2)[((l >> 1) * 17 + dl_c) * 4 + ((l & 1) ? 2 : 0)] = dlt;
        }
        __syncthreads();

        // issue next chunk's global loads early (overlap with recurrence)
        if (l0 + CHUNK < SEQ) LOAD_CHUNK(l0 + CHUNK);

        // ---- recurrence: 2 timesteps per iteration, 1 b128 read per array ----
        #pragma unroll 4
        for (int l2 = 0; l2 < CHUNK / 2; ++l2) {
            const float4 dx4 = sDX2[l2 * 17 + dl];
            const float4 bc4 = sBC2[l2 * 16 + n];
            const float e0 = __expf(dx4.x * An);
            h = fmaf(e0, h, dx4.x * dx4.y * bc4.x);
            const float p0 = rowsum16(h * bc4.y);
            const float e1 = __expf(dx4.z * An);
            h = fmaf(e1, h, dx4.z * dx4.w * bc4.z);
            const float p1 = rowsum16(h * bc4.w);
            if (n == 0) sY2[l2 * 17 + dl] = make_float2(p0, p1);
        }
        __syncthreads();

        // ---- store: y = (p + D*x) * silu(z) ----
        #pragma unroll
        for (int it = 0; it < 2; ++it) {
            const int idx = it * 256 + tid;
            const int l = idx >> 2, q = idx & 3;
            const size_t row = (size_t)(b * SEQ + l0 + l);
            const ushort4 zu = (it == 0) ? zc0 : zc1;
            const float zf[4] = {bf2f(zu.x), bf2f(zu.y), bf2f(zu.z), bf2f(zu.w)};
            const float dd[4] = {ddv.x, ddv.y, ddv.z, ddv.w};
            ushort4 o;
            unsigned short* op = (unsigned short*)&o;
            #pragma unroll
            for (int j = 0; j < 4; ++j) {
                const float p  = ((const float*)sY2)[((l >> 1) * 17 + q * 4 + j) * 2 + (l & 1)];
                const float xv = ((const float*)sDX2)[((l >> 1) * 17 + q * 4 + j) * 4 + ((l & 1) ? 3 : 1)];
                const float yv = fmaf(dd[j], xv, p);
                op[j] = f2bf(yv * zf[j] * sigmoidf_(zf[j]));
            }
            *(ushort4*)&y[row * D_INNER + d0 + q * 4] = o;
        }
        __syncthreads();   // store reads sDX2/sY2; next chunk's writes must wait
    }
    #undef LOAD_CHUNK
}

// fused decoder: out[b] = relu(h_last @ w1.T + b1) @ w2 + b2; one block per batch
__global__ __launch_bounds__(256) void dec_kernel(
    const float* __restrict__ h, const float* __restrict__ w1, const float* __restrict__ b1,
    const float* __restrict__ w2, const float* __restrict__ b2, float* __restrict__ out)
{
    __shared__ __align__(16) float hr[D_MODEL];
    __shared__ float part[4];
    const int b = blockIdx.x, j = threadIdx.x;
    const float* row = h + ((size_t)(b * SEQ + SEQ - 1)) * D_MODEL;
    hr[j] = row[j];
    hr[j + 256] = row[j + 256];
    __syncthreads();
    float acc = b1[j];
    const float* wr = w1 + (size_t)j * D_MODEL;
    for (int k = 0; k < D_MODEL; k += 4) {
        const float4 wvv = *(const float4*)&wr[k];
        const float4 hv = *(const float4*)&hr[k];
        acc = fmaf(wvv.x, hv.x, acc); acc = fmaf(wvv.y, hv.y, acc);
        acc = fmaf(wvv.z, hv.z, acc); acc = fmaf(wvv.w, hv.w, acc);
    }
    float s = fmaxf(acc, 0.f) * w2[j];
    #pragma unroll
    for (int off = 32; off > 0; off >>= 1) s += __shfl_down(s, off, 64);
    if ((j & 63) == 0) part[j >> 6] = s;
    __syncthreads();
    if (j == 0) out[b] = part[0] + part[1] + part[2] + part[3] + b2[0];
}

extern "C" void kernel_launch(void* const* d_in, const int* in_sizes, int n_in,
                              void* d_out, int out_size, void* d_ws, size_t ws_size,
                              hipStream_t stream)
{
    const float* x      = (const float*)d_in[0];
    const float* enc_w  = (const float*)d_in[1];
    const float* enc_b  = (const float*)d_in[2];
    const float* in_w   = (const float*)d_in[3];
    const float* conv_w = (const float*)d_in[4];
    const float* conv_b = (const float*)d_in[5];
    const float* xp_w   = (const float*)d_in[6];
    const float* dtp_w  = (const float*)d_in[7];
    const float* dtp_b  = (const float*)d_in[8];
    const float* A_log  = (const float*)d_in[9];
    const float* Dp     = (const float*)d_in[10];
    const float* out_w  = (const float*)d_in[11];
    const float* norm_w = (const float*)d_in[12];
    const float* dec_w1 = (const float*)d_in[13];
    const float* dec_b1 = (const float*)d_in[14];
    const float* dec_w2 = (const float*)d_in[15];
    const float* dec_b2 = (const float*)d_in[16];
    float* out = (float*)d_out;

    // workspace layout
    float* ws    = (float*)d_ws;
    float* h     = ws;                                   // NTOK*512 fp32
    float* dbc   = h + (size_t)NTOK * D_MODEL;           // NTOK*64 fp32
    float* wsend = dbc + (size_t)NTOK * 64;
    unsigned short* xz_bf   = (unsigned short*)(wsend);                              // NTOK*2048
    unsigned short* xn_bf   = xz_bf   + (size_t)NTOK * 2 * D_INNER;                  // NTOK*512
    unsigned short* y_bf    = xn_bf   + (size_t)NTOK * D_MODEL;                      // NTOK*1024
    unsigned short* xr_bf   = y_bf    + (size_t)NTOK * D_INNER;                      // NTOK*1024
    unsigned short* inw_bf  = xr_bf   + (size_t)NTOK * D_INNER;                      // 4*2048*512
    unsigned short* outw_bf = inw_bf  + (size_t)N_LAYERS * 2 * D_INNER * D_MODEL;    // 4*512*1024
    unsigned short* xpw_bf  = outw_bf + (size_t)N_LAYERS * D_MODEL * D_INNER;        // 4*64*1024

    const int qa = N_LAYERS * 2 * D_INNER * D_MODEL / 4;   // in_proj  vec4 count
    const int qb = N_LAYERS * D_MODEL * D_INNER / 4;       // out_proj
    const int qc = N_LAYERS * 64 * D_INNER / 4;            // x_proj
    cast_all_kernel<<<(qa + qb + qc + 255) / 256, 256, 0, stream>>>(
        in_w, inw_bf, qa, out_w, outw_bf, qb, xp_w, xpw_bf, qc);

    // encoder: h = x @ enc_w.T + enc_b   (fp32, K=32)
    gemm_bt64<<<dim3(D_MODEL / 64, NTOK / 64), 256, 0, stream>>>(
        x, IN_DIM, enc_w, enc_b, h, D_MODEL, IN_DIM, D_MODEL);

    for (int i = 0; i < N_LAYERS; ++i) {
        rmsnorm_kernel<<<NTOK, 256, 0, stream>>>(h, norm_w + (size_t)i * D_MODEL, xn_bf);

        // xz = xn @ in_proj_w[i].T  (4096 x 2048, K=512) [bf16 MFMA, bf16 out]
        gemm_mfma<128, 128, true, false><<<dim3(2 * D_INNER / 128, NTOK / 128), 256, 0, stream>>>(
            xn_bf, D_MODEL, inw_bf + (size_t)i * 2 * D_INNER * D_MODEL, D_MODEL,
            nullptr, xz_bf, 2 * D_INNER, D_MODEL);

        // xr_bf = bf16(silu(causal_dwconv(xz x-half) + cb))
        conv_silu_kernel<<<NTOK * D_INNER / 256, 256, 0, stream>>>(
            xz_bf, conv_w + (size_t)i * D_INNER * D_CONV, conv_b + (size_t)i * D_INNER, xr_bf);

        // dbc = xr @ x_proj_w[i].T  (4096 x 64, K=1024) [bf16 MFMA, fp32 out, BC interleaved]
        gemm_mfma<64, 64, false, true><<<dim3(1, NTOK / 64), 256, 0, stream>>>(
            xr_bf, D_INNER, xpw_bf + (size_t)i * 64 * D_INNER, D_INNER,
            nullptr, dbc, 64, D_INNER);

        // fused dt_proj + scan + D skip + silu(z) gate; y -> bf16
        scan_kernel<<<dim3(D_INNER / 16, BATCH), 256, 0, stream>>>(
            dbc, xr_bf, xz_bf,
            dtp_w + (size_t)i * D_INNER * DT_RANK, dtp_b + (size_t)i * D_INNER,
            A_log + (size_t)i * D_INNER * D_STATE, Dp + (size_t)i * D_INNER, y_bf);

        // h = h + y @ out_proj_w[i].T  (4096 x 512, K=1024) [bf16 MFMA, fp32 out + residual]
        gemm_mfma<128, 64, false, false><<<dim3(D_MODEL / 64, NTOK / 128), 256, 0, stream>>>(
            y_bf, D_INNER, outw_bf + (size_t)i * D_MODEL * D_INNER, D_INNER,
            h, h, D_MODEL, D_INNER);
    }

    dec_kernel<<<BATCH, 256, 0, stream>>>(h, dec_w1, dec_b1, dec_w2, dec_b2, out);
}

// Round 12
// 737.181 us; speedup vs baseline: 1.0732x; 1.0172x over previous
//
#include <hip/hip_runtime.h>
#include <math.h>

#define BATCH   8
#define SEQ     512
#define IN_DIM  32
#define D_MODEL 512
#define N_LAYERS 4
#define D_INNER 1024
#define D_STATE 16
#define D_CONV  4
#define DT_RANK 32
#define NTOK    (BATCH * SEQ)   // 4096
#define CHUNK   128             // scan L-chunk staged in LDS

typedef __attribute__((ext_vector_type(8))) short short8_t;
typedef __attribute__((ext_vector_type(4))) float floatx4;

__device__ __forceinline__ float sigmoidf_(float x) { return 1.f / (1.f + __expf(-x)); }

// fp32 -> bf16 round-to-nearest-even (finite inputs)
__device__ __forceinline__ unsigned short f2bf(float f) {
    unsigned int u = __float_as_uint(f);
    return (unsigned short)((u + 0x7fffu + ((u >> 16) & 1u)) >> 16);
}
__device__ __forceinline__ float bf2f(unsigned short u) {
    return __uint_as_float((unsigned int)u << 16);
}

// sum x across each 16-lane row group via DPP (VALU pipe, no LDS traffic)
__device__ __forceinline__ float rowsum16(float x) {
    int t;
    t = __builtin_amdgcn_update_dpp(0, __float_as_int(x), 0xB1, 0xF, 0xF, true);  // quad_perm [1,0,3,2]
    x += __int_as_float(t);
    t = __builtin_amdgcn_update_dpp(0, __float_as_int(x), 0x4E, 0xF, 0xF, true);  // quad_perm [2,3,0,1]
    x += __int_as_float(t);
    t = __builtin_amdgcn_update_dpp(0, __float_as_int(x), 0x124, 0xF, 0xF, true); // row_ror:4
    x += __int_as_float(t);
    t = __builtin_amdgcn_update_dpp(0, __float_as_int(x), 0x128, 0xF, 0xF, true); // row_ror:8
    x += __int_as_float(t);
    return x;
}

// one-shot fp32->bf16 cast of the three MFMA weight tensors (single dispatch)
__global__ __launch_bounds__(256) void cast_all_kernel(
    const float* __restrict__ a, unsigned short* __restrict__ oa, int qa,   // vec4 counts
    const float* __restrict__ b, unsigned short* __restrict__ ob, int qb,
    const float* __restrict__ c, unsigned short* __restrict__ oc, int qc)
{
    int v = blockIdx.x * 256 + threadIdx.x;
    const float* in; unsigned short* out;
    if (v < qa)                { in = a; out = oa; }
    else if (v < qa + qb)      { v -= qa; in = b; out = ob; }
    else if (v < qa + qb + qc) { v -= qa + qb; in = c; out = oc; }
    else return;
    const float4 x = *(const float4*)&in[v * 4];
    ushort4 o;
    o.x = f2bf(x.x); o.y = f2bf(x.y); o.z = f2bf(x.z); o.w = f2bf(x.w);
    *(ushort4*)&out[v * 4] = o;
}

// ---------------- bf16 MFMA GEMM with async global->LDS staging ----------------
// Staging: __builtin_amdgcn_global_load_lds width=16; lane i lands at LDS base + i*16B
// (wave-uniform base). No padding allowed -> XOR chunk swizzle on the SOURCE address:
//   LDS row r, 16B-slot s holds source chunk (s ^ ((r>>1)&3)).
// Fragment b128 reads then span all 8 bank-quads across 16 rows (2-way only = free).
// OUTBF=false: C fp32, optional residual R. OUTBF=true: C bf16 (no residual).
// ILV: remap output columns 32..63 to interleaved (B0,C0,B1,C1,...) for the scan.
template<int BM, int BN, bool OUTBF, bool ILV>
__global__ __launch_bounds__(256) void gemm_mfma(
    const unsigned short* __restrict__ A, int lda,
    const unsigned short* __restrict__ W, int ldw,
    const float* __restrict__ R,
    void* __restrict__ Cv, int ldc,
    int K)
{
    constexpr int MT = BM / 32;
    constexpr int NT = BN / 32;
    constexpr int SA = BM / 64;   // A-stage DMA insts per wave
    constexpr int SB = BN / 64;
    __shared__ __align__(16) unsigned short sA[BM * 32];
    __shared__ __align__(16) unsigned short sB[BN * 32];

    const int tid  = threadIdx.x;
    const int lane = tid & 63;
    const int wave = tid >> 6;
    const int wm0  = (wave >> 1) * (BM / 2);
    const int wn0  = (wave & 1) * (BN / 2);
    const int lrow = lane & 15;
    const int m0 = blockIdx.y * BM;
    const int n0 = blockIdx.x * BN;

    // staging source pointers (swizzled chunk), k-invariant
    const unsigned short* aptr[SA];
    const unsigned short* bptr[SB];
    #pragma unroll
    for (int s = 0; s < SA; ++s) {
        const int r = wave * (BM / 4) + s * 16 + (lane >> 2);
        const int cc = (((lane & 3) ^ ((r >> 1) & 3))) * 8;
        aptr[s] = &A[(size_t)(m0 + r) * lda + cc];
    }
    #pragma unroll
    for (int s = 0; s < SB; ++s) {
        const int r = wave * (BN / 4) + s * 16 + (lane >> 2);
        const int cc = (((lane & 3) ^ ((r >> 1) & 3))) * 8;
        bptr[s] = &W[(size_t)(n0 + r) * ldw + cc];
    }
    // fragment read offsets (shorts), k-invariant; chunk = lane>>4 swizzled per row
    int aoff[MT], boff[NT];
    #pragma unroll
    for (int mt = 0; mt < MT; ++mt) {
        const int m = wm0 + mt * 16 + lrow;
        aoff[mt] = m * 32 + (((lane >> 4) ^ ((m >> 1) & 3)) * 8);
    }
    #pragma unroll
    for (int nt = 0; nt < NT; ++nt) {
        const int n = wn0 + nt * 16 + lrow;
        boff[nt] = n * 32 + (((lane >> 4) ^ ((n >> 1) & 3)) * 8);
    }

    floatx4 acc[MT][NT];
    #pragma unroll
    for (int mt = 0; mt < MT; ++mt)
        #pragma unroll
        for (int nt = 0; nt < NT; ++nt)
            acc[mt][nt] = (floatx4){0.f, 0.f, 0.f, 0.f};

    for (int k0 = 0; k0 < K; k0 += 32) {
        #pragma unroll
        for (int s = 0; s < SA; ++s)
            __builtin_amdgcn_global_load_lds(
                (const __attribute__((address_space(1))) void*)(aptr[s] + k0),
                (__attribute__((address_space(3))) void*)&sA[(wave * (BM / 4) + s * 16) * 32],
                16, 0, 0);
        #pragma unroll
        for (int s = 0; s < SB; ++s)
            __builtin_amdgcn_global_load_lds(
                (const __attribute__((address_space(1))) void*)(bptr[s] + k0),
                (__attribute__((address_space(3))) void*)&sB[(wave * (BN / 4) + s * 16) * 32],
                16, 0, 0);
        __syncthreads();
        short8_t af[MT], bfr[NT];
        #pragma unroll
        for (int mt = 0; mt < MT; ++mt)
            af[mt] = *(const short8_t*)&sA[aoff[mt]];
        #pragma unroll
        for (int nt = 0; nt < NT; ++nt)
            bfr[nt] = *(const short8_t*)&sB[boff[nt]];
        #pragma unroll
        for (int mt = 0; mt < MT; ++mt)
            #pragma unroll
            for (int nt = 0; nt < NT; ++nt)
                acc[mt][nt] = __builtin_amdgcn_mfma_f32_16x16x32_bf16(af[mt], bfr[nt], acc[mt][nt], 0, 0, 0);
        __syncthreads();
    }

    #pragma unroll
    for (int mt = 0; mt < MT; ++mt) {
        const int mbase = m0 + wm0 + mt * 16 + (lane >> 4) * 4;
        #pragma unroll
        for (int nt = 0; nt < NT; ++nt) {
            const int n = n0 + wn0 + nt * 16 + (lane & 15);
            int np = n;
            if (ILV) np = (n < 32) ? n : ((n < 48) ? 32 + 2 * (n - 32) : 33 + 2 * (n - 48));
            #pragma unroll
            for (int r = 0; r < 4; ++r) {
                float v = acc[mt][nt][r];
                if (OUTBF) {
                    ((unsigned short*)Cv)[(size_t)(mbase + r) * ldc + np] = f2bf(v);
                } else {
                    if (R) v += R[(size_t)(mbase + r) * ldc + np];
                    ((float*)Cv)[(size_t)(mbase + r) * ldc + np] = v;
                }
            }
        }
    }
}

// ---------------- fp32 vector GEMM (encoder only) ----------------
__global__ __launch_bounds__(256) void gemm_bt64(
    const float* __restrict__ A, int lda,
    const float* __restrict__ W,
    const float* __restrict__ bias,
    float* __restrict__ C,
    int N, int K, int ldc)
{
    __shared__ __align__(16) float As[16][64];
    __shared__ __align__(16) float Ws[16][64];
    const int tid = threadIdx.x;
    const int tx = tid & 15, ty = tid >> 4;
    const int m0 = blockIdx.y * 64, n0 = blockIdx.x * 64;
    const int lm = tid >> 2;
    const int lk = (tid & 3) * 4;

    float acc[4][4] = {};
    for (int k0 = 0; k0 < K; k0 += 16) {
        float4 av = *(const float4*)&A[(size_t)(m0 + lm) * lda + k0 + lk];
        float4 wv = *(const float4*)&W[(size_t)(n0 + lm) * K   + k0 + lk];
        As[lk + 0][lm] = av.x; As[lk + 1][lm] = av.y; As[lk + 2][lm] = av.z; As[lk + 3][lm] = av.w;
        Ws[lk + 0][lm] = wv.x; Ws[lk + 1][lm] = wv.y; Ws[lk + 2][lm] = wv.z; Ws[lk + 3][lm] = wv.w;
        __syncthreads();
        #pragma unroll
        for (int k = 0; k < 16; ++k) {
            float4 a4 = *(const float4*)&As[k][ty * 4];
            float4 b4 = *(const float4*)&Ws[k][tx * 4];
            float a[4] = {a4.x, a4.y, a4.z, a4.w};
            float b[4] = {b4.x, b4.y, b4.z, b4.w};
            #pragma unroll
            for (int i = 0; i < 4; ++i)
                #pragma unroll
                for (int j = 0; j < 4; ++j)
                    acc[i][j] = fmaf(a[i], b[j], acc[i][j]);
        }
        __syncthreads();
    }
    #pragma unroll
    for (int i = 0; i < 4; ++i) {
        const int m = m0 + ty * 4 + i;
        #pragma unroll
        for (int j = 0; j < 4; ++j) {
            const int n = n0 + tx * 4 + j;
            C[(size_t)m * ldc + n] = acc[i][j] + bias[n];
        }
    }
}

// xn_bf[tok,:] = bf16( h[tok,:] * rsqrt(mean(h^2)+1e-5) * w )
__global__ __launch_bounds__(256) void rmsnorm_kernel(
    const float* __restrict__ h, const float* __restrict__ w, unsigned short* __restrict__ xn)
{
    const int tok = blockIdx.x, tid = threadIdx.x;
    const float* row = h + (size_t)tok * D_MODEL;
    float v0 = row[tid], v1 = row[tid + 256];
    float s = v0 * v0 + v1 * v1;
    #pragma unroll
    for (int off = 32; off > 0; off >>= 1) s += __shfl_down(s, off, 64);
    __shared__ float ss[4];
    if ((tid & 63) == 0) ss[tid >> 6] = s;
    __syncthreads();
    const float total = ss[0] + ss[1] + ss[2] + ss[3];
    const float scale = rsqrtf(total * (1.f / (float)D_MODEL) + 1e-5f);
    unsigned short* orow = xn + (size_t)tok * D_MODEL;
    orow[tid]       = f2bf(v0 * scale * w[tid]);
    orow[tid + 256] = f2bf(v1 * scale * w[tid + 256]);
}

// causal dwconv + silu over bf16 xz x-half -> xr_bf (bf16). Fully coalesced.
__global__ __launch_bounds__(256) void conv_silu_kernel(
    const unsigned short* __restrict__ xz, const float* __restrict__ cw,
    const float* __restrict__ cb, unsigned short* __restrict__ xr_bf)
{
    const int idx = blockIdx.x * 256 + threadIdx.x;   // over NTOK*D_INNER
    const int d   = idx & (D_INNER - 1);
    const int tok = idx >> 10;
    const int l   = tok & (SEQ - 1);
    float acc = cb[d];
    #pragma unroll
    for (int k = 0; k < D_CONV; ++k) {
        const int t = l - (D_CONV - 1) + k;
        if (t >= 0)
            acc = fmaf(bf2f(xz[(size_t)(tok + t - l) * (2 * D_INNER) + d]), cw[d * D_CONV + k], acc);
    }
    const float v = acc * sigmoidf_(acc);
    xr_bf[(size_t)tok * D_INNER + d] = f2bf(v);
}

// ---------------- fused dt_proj + selective scan + gate ----------------
// Delta-dot reads dbc rows DIRECTLY from global (L2-hot, 16-way lane broadcast).
// Recurrence operands pair-packed (two timesteps per b128 read).
__global__ __launch_bounds__(256) void scan_kernel(
    const float* __restrict__ dbc,   const unsigned short* __restrict__ xrbf,
    const unsigned short* __restrict__ xzbf, const float* __restrict__ dtp_w,
    const float* __restrict__ dtp_b, const float* __restrict__ A_log,
    const float* __restrict__ Dp,    unsigned short* __restrict__ y)
{
    __shared__ __align__(16) float4 sBC2[(CHUNK/2) * 16];     // 16 KB
    __shared__ __align__(16) float4 sDX2[(CHUNK/2) * 17];     // 17.4 KB
    __shared__ __align__(16) float2 sY2 [(CHUNK/2) * 17];     // 8.7 KB
    const int b   = blockIdx.y;
    const int tid = threadIdx.x;
    const int n   = tid & 15;
    const int dl  = tid >> 4;
    const int d0  = blockIdx.x * 16;
    const int dl_c = tid & 15;      // delta-phase channel
    const int lg   = tid >> 4;      // delta-phase l-group (0..15)
    const int prow = tid >> 1, phalf = tid & 1;   // x-staging mapping

    // per-thread dt_proj weight row
    float4 wv[8];
    {
        const float* wr = dtp_w + (size_t)(d0 + dl_c) * DT_RANK;
        #pragma unroll
        for (int q = 0; q < 8; ++q) wv[q] = *(const float4*)&wr[q * 4];
    }
    const float dtb = dtp_b[d0 + dl_c];
    const float An = -__expf(A_log[(size_t)(d0 + dl) * D_STATE + n]);
    // store-phase D row (q = tid&3 fixed per thread)
    const float4 ddv = *(const float4*)&Dp[d0 + (tid & 3) * 4];

    // prefetch registers (B/C pairs, x, z)
    float2 pbe[4], pbo[4];
    short8_t pxv;
    ushort4  pzv[2];

    #define LOAD_CHUNK(L0)                                                                  \
    {                                                                                       \
        _Pragma("unroll")                                                                   \
        for (int it = 0; it < 4; ++it) {                                                    \
            const int u = it * 256 + tid;                                                   \
            const int l2 = u >> 4, nu = u & 15;                                             \
            pbe[it] = *(const float2*)&dbc[((size_t)(b * SEQ + (L0) + 2 * l2))     * 64 + 32 + 2 * nu]; \
            pbo[it] = *(const float2*)&dbc[((size_t)(b * SEQ + (L0) + 2 * l2 + 1)) * 64 + 32 + 2 * nu]; \
        }                                                                                   \
        pxv = *(const short8_t*)&xrbf[((size_t)(b * SEQ + (L0) + prow)) * D_INNER + d0 + phalf * 8];   \
        _Pragma("unroll")                                                                   \
        for (int it = 0; it < 2; ++it) {                                                    \
            const int u = it * 256 + tid;                                                   \
            pzv[it] = *(const ushort4*)&xzbf[((size_t)(b * SEQ + (L0) + (u >> 2))) * (2 * D_INNER) + D_INNER + d0 + (u & 3) * 4]; \
        }                                                                                   \
    }

    LOAD_CHUNK(0);
    float h = 0.f;
    for (int l0 = 0; l0 < SEQ; l0 += CHUNK) {
        // ---- write prefetched regs to LDS ----
        #pragma unroll
        for (int it = 0; it < 4; ++it) {
            const int u = it * 256 + tid;
            sBC2[(u >> 4) * 16 + (u & 15)] = make_float4(pbe[it].x, pbe[it].y, pbo[it].x, pbo[it].y);
        }
        {
            const int base = ((prow >> 1) * 17) * 4 + ((prow & 1) ? 3 : 1);
            #pragma unroll
            for (int j = 0; j < 8; ++j)
                ((float*)sDX2)[base + (phalf * 8 + j) * 4] = bf2f((unsigned short)pxv[j]);
        }
        const ushort4 zc0 = pzv[0], zc1 = pzv[1];   // capture z of current chunk

        // ---- delta = softplus(dt @ W + b): dt rows read from GLOBAL (broadcast) ----
        #pragma unroll
        for (int ls = 0; ls < 8; ++ls) {
            const int l = ls * 16 + lg;
            const float* dtrow = &dbc[((size_t)(b * SEQ + l0 + l)) * 64];
            float a = dtb;
            #pragma unroll
            for (int q = 0; q < 8; ++q) {
                const float4 t4 = *(const float4*)&dtrow[q * 4];
                a = fmaf(t4.x, wv[q].x, a); a = fmaf(t4.y, wv[q].y, a);
                a = fmaf(t4.z, wv[q].z, a); a = fmaf(t4.w, wv[q].w, a);
            }
            const float dlt = (a > 20.f) ? a : log1pf(__expf(a));
            ((float*)sDX2)[((l >> 1) * 17 + dl_c) * 4 + ((l & 1) ? 2 : 0)] = dlt;
        }
        __syncthreads();

        // issue next chunk's global loads early (overlap with recurrence)
        if (l0 + CHUNK < SEQ) LOAD_CHUNK(l0 + CHUNK);

        // ---- recurrence: 2 timesteps per iteration, 1 b128 read per array ----
        #pragma unroll 4
        for (int l2 = 0; l2 < CHUNK / 2; ++l2) {
            const float4 dx4 = sDX2[l2 * 17 + dl];
            const float4 bc4 = sBC2[l2 * 16 + n];
            const float e0 = __expf(dx4.x * An);
            h = fmaf(e0, h, dx4.x * dx4.y * bc4.x);
            const float p0 = rowsum16(h * bc4.y);
            const float e1 = __expf(dx4.z * An);
            h = fmaf(e1, h, dx4.z * dx4.w * bc4.z);
            const float p1 = rowsum16(h * bc4.w);
            if (n == 0) sY2[l2 * 17 + dl] = make_float2(p0, p1);
        }
        __syncthreads();

        // ---- store: y = (p + D*x) * silu(z) ----
        #pragma unroll
        for (int it = 0; it < 2; ++it) {
            const int idx = it * 256 + tid;
            const int l = idx >> 2, q = idx & 3;
            const size_t row = (size_t)(b * SEQ + l0 + l);
            const ushort4 zu = (it == 0) ? zc0 : zc1;
            const float zf[4] = {bf2f(zu.x), bf2f(zu.y), bf2f(zu.z), bf2f(zu.w)};
            const float dd[4] = {ddv.x, ddv.y, ddv.z, ddv.w};
            ushort4 o;
            unsigned short* op = (unsigned short*)&o;
            #pragma unroll
            for (int j = 0; j < 4; ++j) {
                const float p  = ((const float*)sY2)[((l >> 1) * 17 + q * 4 + j) * 2 + (l & 1)];
                const float xv = ((const float*)sDX2)[((l >> 1) * 17 + q * 4 + j) * 4 + ((l & 1) ? 3 : 1)];
                const float yv = fmaf(dd[j], xv, p);
                op[j] = f2bf(yv * zf[j] * sigmoidf_(zf[j]));
            }
            *(ushort4*)&y[row * D_INNER + d0 + q * 4] = o;
        }
        __syncthreads();   // store reads sDX2/sY2; next chunk's writes must wait
    }
    #undef LOAD_CHUNK
}

// fused decoder: out[b] = relu(h_last @ w1.T + b1) @ w2 + b2; one block per batch
__global__ __launch_bounds__(256) void dec_kernel(
    const float* __restrict__ h, const float* __restrict__ w1, const float* __restrict__ b1,
    const float* __restrict__ w2, const float* __restrict__ b2, float* __restrict__ out)
{
    __shared__ __align__(16) float hr[D_MODEL];
    __shared__ float part[4];
    const int b = blockIdx.x, j = threadIdx.x;
    const float* row = h + ((size_t)(b * SEQ + SEQ - 1)) * D_MODEL;
    hr[j] = row[j];
    hr[j + 256] = row[j + 256];
    __syncthreads();
    float acc = b1[j];
    const float* wr = w1 + (size_t)j * D_MODEL;
    for (int k = 0; k < D_MODEL; k += 4) {
        const float4 wvv = *(const float4*)&wr[k];
        const float4 hv = *(const float4*)&hr[k];
        acc = fmaf(wvv.x, hv.x, acc); acc = fmaf(wvv.y, hv.y, acc);
        acc = fmaf(wvv.z, hv.z, acc); acc = fmaf(wvv.w, hv.w, acc);
    }
    float s = fmaxf(acc, 0.f) * w2[j];
    #pragma unroll
    for (int off = 32; off > 0; off >>= 1) s += __shfl_down(s, off, 64);
    if ((j & 63) == 0) part[j >> 6] = s;
    __syncthreads();
    if (j == 0) out[b] = part[0] + part[1] + part[2] + part[3] + b2[0];
}

extern "C" void kernel_launch(void* const* d_in, const int* in_sizes, int n_in,
                              void* d_out, int out_size, void* d_ws, size_t ws_size,
                              hipStream_t stream)
{
    const float* x      = (const float*)d_in[0];
    const float* enc_w  = (const float*)d_in[1];
    const float* enc_b  = (const float*)d_in[2];
    const float* in_w   = (const float*)d_in[3];
    const float* conv_w = (const float*)d_in[4];
    const float* conv_b = (const float*)d_in[5];
    const float* xp_w   = (const float*)d_in[6];
    const float* dtp_w  = (const float*)d_in[7];
    const float* dtp_b  = (const float*)d_in[8];
    const float* A_log  = (const float*)d_in[9];
    const float* Dp     = (const float*)d_in[10];
    const float* out_w  = (const float*)d_in[11];
    const float* norm_w = (const float*)d_in[12];
    const float* dec_w1 = (const float*)d_in[13];
    const float* dec_b1 = (const float*)d_in[14];
    const float* dec_w2 = (const float*)d_in[15];
    const float* dec_b2 = (const float*)d_in[16];
    float* out = (float*)d_out;

    // workspace layout
    float* ws    = (float*)d_ws;
    float* h     = ws;                                   // NTOK*512 fp32
    float* dbc   = h + (size_t)NTOK * D_MODEL;           // NTOK*64 fp32
    float* wsend = dbc + (size_t)NTOK * 64;
    unsigned short* xz_bf   = (unsigned short*)(wsend);                              // NTOK*2048
    unsigned short* xn_bf   = xz_bf   + (size_t)NTOK * 2 * D_INNER;                  // NTOK*512
    unsigned short* y_bf    = xn_bf   + (size_t)NTOK * D_MODEL;                      // NTOK*1024
    unsigned short* xr_bf   = y_bf    + (size_t)NTOK * D_INNER;                      // NTOK*1024
    unsigned short* inw_bf  = xr_bf   + (size_t)NTOK * D_INNER;                      // 4*2048*512
    unsigned short* outw_bf = inw_bf  + (size_t)N_LAYERS * 2 * D_INNER * D_MODEL;    // 4*512*1024
    unsigned short* xpw_bf  = outw_bf + (size_t)N_LAYERS * D_MODEL * D_INNER;        // 4*64*1024

    const int qa = N_LAYERS * 2 * D_INNER * D_MODEL / 4;   // in_proj  vec4 count
    const int qb = N_LAYERS * D_MODEL * D_INNER / 4;       // out_proj
    const int qc = N_LAYERS * 64 * D_INNER / 4;            // x_proj
    cast_all_kernel<<<(qa + qb + qc + 255) / 256, 256, 0, stream>>>(
        in_w, inw_bf, qa, out_w, outw_bf, qb, xp_w, xpw_bf, qc);

    // encoder: h = x @ enc_w.T + enc_b   (fp32, K=32)
    gemm_bt64<<<dim3(D_MODEL / 64, NTOK / 64), 256, 0, stream>>>(
        x, IN_DIM, enc_w, enc_b, h, D_MODEL, IN_DIM, D_MODEL);

    for (int i = 0; i < N_LAYERS; ++i) {
        rmsnorm_kernel<<<NTOK, 256, 0, stream>>>(h, norm_w + (size_t)i * D_MODEL, xn_bf);

        // xz = xn @ in_proj_w[i].T  (4096 x 2048, K=512) [bf16 MFMA, bf16 out]
        gemm_mfma<128, 128, true, false><<<dim3(2 * D_INNER / 128, NTOK / 128), 256, 0, stream>>>(
            xn_bf, D_MODEL, inw_bf + (size_t)i * 2 * D_INNER * D_MODEL, D_MODEL,
            nullptr, xz_bf, 2 * D_INNER, D_MODEL);

        // xr_bf = bf16(silu(causal_dwconv(xz x-half) + cb))
        conv_silu_kernel<<<NTOK * D_INNER / 256, 256, 0, stream>>>(
            xz_bf, conv_w + (size_t)i * D_INNER * D_CONV, conv_b + (size_t)i * D_INNER, xr_bf);

        // dbc = xr @ x_proj_w[i].T  (4096 x 64, K=1024) [bf16 MFMA, fp32 out, BC interleaved]
        gemm_mfma<64, 64, false, true><<<dim3(1, NTOK / 64), 256, 0, stream>>>(
            xr_bf, D_INNER, xpw_bf + (size_t)i * 64 * D_INNER, D_INNER,
            nullptr, dbc, 64, D_INNER);

        // fused dt_proj + scan + D skip + silu(z) gate; y -> bf16
        scan_kernel<<<dim3(D_INNER / 16, BATCH), 256, 0, stream>>>(
            dbc, xr_bf, xz_bf,
            dtp_w + (size_t)i * D_INNER * DT_RANK, dtp_b + (size_t)i * D_INNER,
            A_log + (size_t)i * D_INNER * D_STATE, Dp + (size_t)i * D_INNER, y_bf);

        // h = h + y @ out_proj_w[i].T  (4096 x 512, K=1024) [bf16 MFMA, fp32 out + residual]
        gemm_mfma<128, 64, false, false><<<dim3(D_MODEL / 64, NTOK / 128), 256, 0, stream>>>(
            y_bf, D_INNER, outw_bf + (size_t)i * D_MODEL * D_INNER, D_INNER,
            h, h, D_MODEL, D_INNER);
    }

    dec_kernel<<<BATCH, 256, 0, stream>>>(h, dec_w1, dec_b1, dec_w2, dec_b2, out);
}